// Round 2
// baseline (5516.446 us; speedup 1.0000x reference)
//
#include <hip/hip_runtime.h>

#define NPTS 1000000
#define KNBR 27
#define NCH 64
#define EPSV 1e-5f
#define CONV_TPB 128   // threads per conv block
#define CONV_TP  128   // points per conv block

// ---------------------------------------------------------------------------
// Mask dtype autodetect: harness canonicalizes dtypes; JAX bool is most likely
// int32 on device, but could be uint8. View as u32: int32 0/1 data => words
// are all <=1; bool bytes viewed as u32 are <=1 only when 3 high bytes are 0
// (p ~ 0.3^3 = 2.7%). Count over 4096 words, threshold at 95%.
// flag = 1 -> int32 mask, flag = 0 -> uint8 mask.
// ---------------------------------------------------------------------------
__global__ void detect_mask_kernel(const unsigned int* __restrict__ mask32,
                                   int* __restrict__ flag)
{
    __shared__ int cnt;
    if (threadIdx.x == 0) cnt = 0;
    __syncthreads();
    int c = 0;
    for (int i = threadIdx.x; i < 4096; i += 256)
        if (mask32[i] <= 1u) c++;
    atomicAdd(&cnt, c);
    __syncthreads();
    if (threadIdx.x == 0) *flag = (cnt >= 3900) ? 1 : 0;
}

// ---------------------------------------------------------------------------
// Gather-GEMM conv: out[n,co] = sum_k sum_ci src[nbr[n,k],ci] * mask[n,k] * W[k,ci,co]
// Block: 128 points x 64 couts. 128 threads, 8x8 register tile each.
// LDS: W slice [CIN][64] + transposed gather tile g[CIN][128].
// ---------------------------------------------------------------------------
template<int CIN>
__global__ __launch_bounds__(CONV_TPB)
void conv_kernel(const float* __restrict__ src,
                 const float* __restrict__ W,
                 const int*  __restrict__ nbr,
                 const unsigned char* __restrict__ mask8,
                 const int*  __restrict__ mask32,
                 const int*  __restrict__ mflag,
                 float* __restrict__ out)
{
    __shared__ float W_s[CIN * NCH];      // conv1: 8KB, conv2: 16KB
    __shared__ float g_s[CIN * CONV_TP];  // conv1: 16KB, conv2: 32KB

    const int t = threadIdx.x;
    const int pbase = blockIdx.x * CONV_TP;
    const int p = pbase + t;              // this thread's gather point
    const bool pvalid = (p < NPTS);
    const int pK = pvalid ? p * KNBR : 0;
    const bool m_is_i32 = (*mflag != 0);  // uniform

    float acc[8][8];
#pragma unroll
    for (int i = 0; i < 8; ++i)
#pragma unroll
        for (int j = 0; j < 8; ++j)
            acc[i][j] = 0.0f;

    const int pp = t >> 3;   // point group: points pp*8 .. pp*8+7
    const int cc = t & 7;    // cout group:  couts cc*8 .. cc*8+7

    for (int k = 0; k < KNBR; ++k) {
        __syncthreads();  // protect LDS from previous iteration's readers
        // ---- stage W[k] -> LDS (coalesced float4) ----
        {
            const float4* Wg = (const float4*)(W + k * (CIN * NCH));
            float4* Ws = (float4*)W_s;
#pragma unroll
            for (int i = 0; i < (CIN * NCH / 4) / CONV_TPB; ++i)
                Ws[t + i * CONV_TPB] = Wg[t + i * CONV_TPB];
        }
        // ---- gather this thread's point row, masked, write transposed ----
        int idx = 0;
        float fm = 0.0f;
        if (pvalid) {
            idx = nbr[pK + k];
            const bool mb = m_is_i32 ? (mask32[pK + k] != 0)
                                     : (mask8[pK + k] != 0);
            fm = mb ? 1.0f : 0.0f;  // mask applied as multiply (uniform flow)
        }
        const float4* row = (const float4*)(src + (size_t)idx * CIN);
#pragma unroll
        for (int ch = 0; ch < CIN / 16; ++ch) {
            float4 v0 = row[ch * 4 + 0];
            float4 v1 = row[ch * 4 + 1];
            float4 v2 = row[ch * 4 + 2];
            float4 v3 = row[ch * 4 + 3];
            const int cb = ch * 16;
            g_s[(cb +  0) * CONV_TP + t] = v0.x * fm;
            g_s[(cb +  1) * CONV_TP + t] = v0.y * fm;
            g_s[(cb +  2) * CONV_TP + t] = v0.z * fm;
            g_s[(cb +  3) * CONV_TP + t] = v0.w * fm;
            g_s[(cb +  4) * CONV_TP + t] = v1.x * fm;
            g_s[(cb +  5) * CONV_TP + t] = v1.y * fm;
            g_s[(cb +  6) * CONV_TP + t] = v1.z * fm;
            g_s[(cb +  7) * CONV_TP + t] = v1.w * fm;
            g_s[(cb +  8) * CONV_TP + t] = v2.x * fm;
            g_s[(cb +  9) * CONV_TP + t] = v2.y * fm;
            g_s[(cb + 10) * CONV_TP + t] = v2.z * fm;
            g_s[(cb + 11) * CONV_TP + t] = v2.w * fm;
            g_s[(cb + 12) * CONV_TP + t] = v3.x * fm;
            g_s[(cb + 13) * CONV_TP + t] = v3.y * fm;
            g_s[(cb + 14) * CONV_TP + t] = v3.z * fm;
            g_s[(cb + 15) * CONV_TP + t] = v3.w * fm;
        }
        __syncthreads();
        // ---- 8x8 outer-product accumulate over ci ----
#pragma unroll 2
        for (int ci = 0; ci < CIN; ++ci) {
            const float4 ga = *(const float4*)&g_s[ci * CONV_TP + pp * 8];
            const float4 gb = *(const float4*)&g_s[ci * CONV_TP + pp * 8 + 4];
            const float4 wa = *(const float4*)&W_s[ci * NCH + cc * 8];
            const float4 wb = *(const float4*)&W_s[ci * NCH + cc * 8 + 4];
            const float gv[8] = {ga.x, ga.y, ga.z, ga.w, gb.x, gb.y, gb.z, gb.w};
            const float wv[8] = {wa.x, wa.y, wa.z, wa.w, wb.x, wb.y, wb.z, wb.w};
#pragma unroll
            for (int i = 0; i < 8; ++i)
#pragma unroll
                for (int j = 0; j < 8; ++j)
                    acc[i][j] = fmaf(gv[i], wv[j], acc[i][j]);
        }
    }
    // ---- epilogue: raw conv output (BN applied in a later pass) ----
#pragma unroll
    for (int i = 0; i < 8; ++i) {
        const int gp = pbase + pp * 8 + i;
        if (gp < NPTS) {
            float* op = out + (size_t)gp * NCH + cc * 8;
            *(float4*)op       = make_float4(acc[i][0], acc[i][1], acc[i][2], acc[i][3]);
            *(float4*)(op + 4) = make_float4(acc[i][4], acc[i][5], acc[i][6], acc[i][7]);
        }
    }
}

// ---------------------------------------------------------------------------
// Per-channel sum & sumsq over [N,64]; channel = element_index % 64 == t % 64.
// ---------------------------------------------------------------------------
__global__ __launch_bounds__(256)
void stats_kernel(const float* __restrict__ x, float* __restrict__ sums)
{
    __shared__ float red[512];
    const int t = threadIdx.x;
    const long total = (long)NPTS * NCH;
    const long stride = (long)gridDim.x * 256;
    float s = 0.0f, q = 0.0f;
    for (long i = (long)blockIdx.x * 256 + t; i < total; i += stride) {
        float v = x[i];
        s += v;
        q = fmaf(v, v, q);
    }
    red[t] = s;
    red[256 + t] = q;
    __syncthreads();
    if (t < 128) {
        red[t]       += red[t + 128];
        red[256 + t] += red[256 + t + 128];
    }
    __syncthreads();
    if (t < 64) {
        atomicAdd(&sums[t],      red[t]       + red[t + 64]);
        atomicAdd(&sums[64 + t], red[256 + t] + red[256 + t + 64]);
    }
}

// sums -> folded scale/shift:  bn(x) = x*scale + shift
__global__ void finalize_kernel(const float* __restrict__ sums,
                                const float* __restrict__ gamma,
                                const float* __restrict__ beta,
                                float* __restrict__ ss)
{
    const int c = threadIdx.x;
    if (c < NCH) {
        const float inv = 1.0f / (float)NPTS;
        float mu  = sums[c] * inv;
        float var = sums[NCH + c] * inv - mu * mu;   // biased var (jnp.var default)
        float rs  = 1.0f / sqrtf(var + EPSV);
        float scv = gamma[c] * rs;
        ss[c]       = scv;
        ss[NCH + c] = beta[c] - mu * scv;
    }
}

// In-place y = relu(x*scale + shift), vectorized float4. Channel phase is
// constant per-thread because every stride is a multiple of 64 floats.
__global__ __launch_bounds__(256)
void bnrelu_kernel(float* __restrict__ x, const float* __restrict__ ss, long n4)
{
    const int t = threadIdx.x;
    const int c0 = (t * 4) & 63;
    const float4 sc = *(const float4*)&ss[c0];
    const float4 sh = *(const float4*)&ss[NCH + c0];
    const long stride = (long)gridDim.x * 256;
    float4* x4 = (float4*)x;
    for (long i = (long)blockIdx.x * 256 + t; i < n4; i += stride) {
        float4 v = x4[i];
        v.x = fmaxf(fmaf(v.x, sc.x, sh.x), 0.0f);
        v.y = fmaxf(fmaf(v.y, sc.y, sh.y), 0.0f);
        v.z = fmaxf(fmaf(v.z, sc.z, sh.z), 0.0f);
        v.w = fmaxf(fmaf(v.w, sc.w, sh.w), 0.0f);
        x4[i] = v;
    }
}

extern "C" void kernel_launch(void* const* d_in, const int* in_sizes, int n_in,
                              void* d_out, int out_size, void* d_ws, size_t ws_size,
                              hipStream_t stream)
{
    const float* feats  = (const float*)d_in[0];
    const float* W1     = (const float*)d_in[1];
    const float* W2     = (const float*)d_in[2];
    const float* gamma1 = (const float*)d_in[3];
    const float* beta1  = (const float*)d_in[4];
    const float* gamma2 = (const float*)d_in[5];
    const float* beta2  = (const float*)d_in[6];
    const int* nbr      = (const int*)d_in[7];
    const unsigned char* mask8 = (const unsigned char*)d_in[8];
    const int* mask32          = (const int*)d_in[8];
    float* out = (float*)d_out;

    // workspace: h1 [N,64] fp32 (256 MB) + stats + mask flag
    float* h1    = (float*)d_ws;
    float* stats = (float*)((char*)d_ws + (size_t)NPTS * NCH * sizeof(float));
    int*   mflag = (int*)(stats + 512);
    // stats layout: [0:128) sums1 | [128:256) scale/shift1 | [256:384) sums2 | [384:512) ss2

    hipMemsetAsync(stats, 0, 512 * sizeof(float), stream);

    const int conv_grid = (NPTS + CONV_TP - 1) / CONV_TP;  // 7813
    const long n4 = (long)NPTS * NCH / 4;

    detect_mask_kernel<<<1, 256, 0, stream>>>((const unsigned int*)d_in[8], mflag);

    conv_kernel<32><<<conv_grid, CONV_TPB, 0, stream>>>(feats, W1, nbr, mask8, mask32, mflag, h1);
    stats_kernel<<<1024, 256, 0, stream>>>(h1, stats);
    finalize_kernel<<<1, 64, 0, stream>>>(stats, gamma1, beta1, stats + 128);
    bnrelu_kernel<<<2048, 256, 0, stream>>>(h1, stats + 128, n4);

    conv_kernel<64><<<conv_grid, CONV_TPB, 0, stream>>>(h1, W2, nbr, mask8, mask32, mflag, out);
    stats_kernel<<<1024, 256, 0, stream>>>(out, stats + 256);
    finalize_kernel<<<1, 64, 0, stream>>>(stats + 256, gamma2, beta2, stats + 384);
    bnrelu_kernel<<<2048, 256, 0, stream>>>(out, stats + 384, n4);
}

// Round 3
// 2913.733 us; speedup vs baseline: 1.8933x; 1.8933x over previous
//
#include <hip/hip_runtime.h>

#define NPTS 1000000
#define KNBR 27
#define NCH 64
#define EPSV 1e-5f

typedef __attribute__((ext_vector_type(8))) short bf16x8;   // 8 bf16 = 4 VGPRs (guide §3)
typedef __attribute__((ext_vector_type(4))) float f32x4;    // MFMA C/D frag
typedef __attribute__((ext_vector_type(8))) unsigned short ushort8;

__device__ inline unsigned short f2bf(float f) {            // RNE fp32->bf16
    unsigned int x = __float_as_uint(f);
    unsigned int r = x + 0x7FFFu + ((x >> 16) & 1u);
    return (unsigned short)(r >> 16);
}
__device__ inline float bf2f(unsigned short u) {
    return __uint_as_float(((unsigned int)u) << 16);
}

// ---------------------------------------------------------------------------
// Mask dtype autodetect (unchanged from R2, which passed).
// ---------------------------------------------------------------------------
__global__ void detect_mask_kernel(const unsigned int* __restrict__ mask32,
                                   int* __restrict__ flag)
{
    __shared__ int cnt;
    if (threadIdx.x == 0) cnt = 0;
    __syncthreads();
    int c = 0;
    for (int i = threadIdx.x; i < 4096; i += 256)
        if (mask32[i] <= 1u) c++;
    atomicAdd(&cnt, c);
    __syncthreads();
    if (threadIdx.x == 0) *flag = (cnt >= 3900) ? 1 : 0;
}

// feats fp32 -> bf16 (32M elems, chunks of 8)
__global__ __launch_bounds__(256)
void cvt_feats_kernel(const float* __restrict__ in, unsigned short* __restrict__ outp)
{
    const long nchunk = (long)NPTS * 32 / 8;   // 4M
    const long stride = (long)gridDim.x * 256;
    const float4* f4 = (const float4*)in;
    ushort8* o8 = (ushort8*)outp;
    for (long i = (long)blockIdx.x * 256 + threadIdx.x; i < nchunk; i += stride) {
        float4 a = f4[2 * i], b = f4[2 * i + 1];
        ushort8 o;
        o[0] = f2bf(a.x); o[1] = f2bf(a.y); o[2] = f2bf(a.z); o[3] = f2bf(a.w);
        o[4] = f2bf(b.x); o[5] = f2bf(b.y); o[6] = f2bf(b.z); o[7] = f2bf(b.w);
        o8[i] = o;
    }
}

// W[k][ci][co] fp32 -> Wt[k][co][ci] bf16 (one block per k)
template<int CIN>
__global__ __launch_bounds__(256)
void transpose_w_kernel(const float* __restrict__ W, unsigned short* __restrict__ wt)
{
    const int k = blockIdx.x;
    for (int e = threadIdx.x; e < CIN * 64; e += 256) {
        int ci = e >> 6, co = e & 63;
        wt[((size_t)(k * 64 + co)) * CIN + ci] = f2bf(W[(size_t)k * CIN * 64 + e]);
    }
}

// ---------------------------------------------------------------------------
// MFMA conv. Block = 256 thr (4 waves) x 64 points; wave handles 16 points x
// 64 couts (4 coltile frags). A-frags gathered DIRECTLY from global bf16 rows
// (lane: row = l&15, k-dims (l>>4)*8+j -> one 16B load). B-frags from
// pre-transposed Wt[k][co][ci] (L2-resident). Masked rows skip the load.
// ---------------------------------------------------------------------------
template<int CIN, bool OUT_BF16>
__global__ __launch_bounds__(256)
void conv_mfma_kernel(const unsigned short* __restrict__ src,  // [N][CIN] bf16
                      const unsigned short* __restrict__ wt,   // [27][64][CIN] bf16
                      const int* __restrict__ nbr,
                      const unsigned char* __restrict__ mask8,
                      const int* __restrict__ mask32,
                      const int* __restrict__ mflag,
                      void* __restrict__ outp)
{
    __shared__ int midx[64 * KNBR];   // neighbor idx, -1 if masked off (6.9 KB)

    const int t = threadIdx.x;
    const int pbase = blockIdx.x * 64;

    // ---- preload nbr+mask, merged (layout matches global [p][k] linear) ----
    const bool m32 = (*mflag != 0);
    for (int i = t; i < 64 * KNBR; i += 256) {
        int idxv = nbr[pbase * KNBR + i];
        bool mv = m32 ? (mask32[pbase * KNBR + i] != 0)
                      : (mask8[pbase * KNBR + i] != 0);
        midx[i] = mv ? idxv : -1;
    }
    __syncthreads();

    const int wave = t >> 6;
    const int lane = t & 63;
    const int lr = lane & 15;    // A row within wave tile / B col within coltile
    const int kg = lane >> 4;    // k-subgroup (8 elems each)
    const int lrow27 = (wave * 16 + lr) * KNBR;

    f32x4 acc[4];
#pragma unroll
    for (int c = 0; c < 4; ++c) acc[c] = (f32x4){0.f, 0.f, 0.f, 0.f};

    const bf16x8 zero8 = {0, 0, 0, 0, 0, 0, 0, 0};

    for (int k = 0; k < KNBR; ++k) {
        const int mi = midx[lrow27 + k];
#pragma unroll
        for (int ks = 0; ks < CIN / 32; ++ks) {
            bf16x8 a = zero8;
            if (mi >= 0)
                a = *(const bf16x8*)(src + (size_t)mi * CIN + ks * 32 + kg * 8);
#pragma unroll
            for (int c = 0; c < 4; ++c) {
                const bf16x8 b = *(const bf16x8*)(wt + ((size_t)(k * 64 + c * 16 + lr)) * CIN
                                                     + ks * 32 + kg * 8);
                acc[c] = __builtin_amdgcn_mfma_f32_16x16x32_bf16(a, b, acc[c], 0, 0, 0);
            }
        }
    }

    // ---- epilogue: D layout col=lane&15, row=(lane>>4)*4+reg (m89-verified) ----
    const int row0 = pbase + wave * 16 + kg * 4;
    if (OUT_BF16) {
        unsigned short* o = (unsigned short*)outp;
#pragma unroll
        for (int c = 0; c < 4; ++c)
#pragma unroll
            for (int r = 0; r < 4; ++r)
                o[(size_t)(row0 + r) * NCH + c * 16 + lr] = f2bf(acc[c][r]);
    } else {
        float* o = (float*)outp;
#pragma unroll
        for (int c = 0; c < 4; ++c)
#pragma unroll
            for (int r = 0; r < 4; ++r)
                o[(size_t)(row0 + r) * NCH + c * 16 + lr] = acc[c][r];
    }
}

// ---------------------------------------------------------------------------
// Per-channel sum/sumsq, bf16 input. Thread t slot j -> channel (t%8)*8+j.
// ---------------------------------------------------------------------------
__global__ __launch_bounds__(256)
void stats_bf16_kernel(const unsigned short* __restrict__ x, float* __restrict__ sums)
{
    __shared__ float rs[2048], rq[2048];
    const int t = threadIdx.x;
    float s[8], q[8];
#pragma unroll
    for (int j = 0; j < 8; ++j) { s[j] = 0.f; q[j] = 0.f; }
    const long nchunk = (long)NPTS * NCH / 8;
    const long stride = (long)gridDim.x * 256;
    const ushort8* x8 = (const ushort8*)x;
    for (long i = (long)blockIdx.x * 256 + t; i < nchunk; i += stride) {
        ushort8 v = x8[i];
#pragma unroll
        for (int j = 0; j < 8; ++j) {
            float f = bf2f(v[j]);
            s[j] += f;
            q[j] = fmaf(f, f, q[j]);
        }
    }
#pragma unroll
    for (int j = 0; j < 8; ++j) { rs[t * 8 + j] = s[j]; rq[t * 8 + j] = q[j]; }
    __syncthreads();
    if (t < 64) {
        const int g = t >> 3, j = t & 7;
        float S = 0.f, Q = 0.f;
        for (int i = 0; i < 32; ++i) {
            const int tt = i * 8 + g;
            S += rs[tt * 8 + j];
            Q += rq[tt * 8 + j];
        }
        atomicAdd(&sums[t], S);
        atomicAdd(&sums[64 + t], Q);
    }
}

// fp32 variant: thread t slot j -> channel (t%16)*4+j
__global__ __launch_bounds__(256)
void stats_f32_kernel(const float* __restrict__ x, float* __restrict__ sums)
{
    __shared__ float rs[1024], rq[1024];
    const int t = threadIdx.x;
    float s[4], q[4];
#pragma unroll
    for (int j = 0; j < 4; ++j) { s[j] = 0.f; q[j] = 0.f; }
    const long nchunk = (long)NPTS * NCH / 4;
    const long stride = (long)gridDim.x * 256;
    const float4* x4 = (const float4*)x;
    for (long i = (long)blockIdx.x * 256 + t; i < nchunk; i += stride) {
        float4 v = x4[i];
        s[0] += v.x; q[0] = fmaf(v.x, v.x, q[0]);
        s[1] += v.y; q[1] = fmaf(v.y, v.y, q[1]);
        s[2] += v.z; q[2] = fmaf(v.z, v.z, q[2]);
        s[3] += v.w; q[3] = fmaf(v.w, v.w, q[3]);
    }
#pragma unroll
    for (int j = 0; j < 4; ++j) { rs[t * 4 + j] = s[j]; rq[t * 4 + j] = q[j]; }
    __syncthreads();
    if (t < 64) {
        const int g = t >> 2, j = t & 3;
        float S = 0.f, Q = 0.f;
        for (int i = 0; i < 16; ++i) {
            const int tt = i * 16 + g;
            S += rs[tt * 4 + j];
            Q += rq[tt * 4 + j];
        }
        atomicAdd(&sums[t], S);
        atomicAdd(&sums[64 + t], Q);
    }
}

// sums -> folded scale/shift:  bn(x) = x*scale + shift
__global__ void finalize_kernel(const float* __restrict__ sums,
                                const float* __restrict__ gamma,
                                const float* __restrict__ beta,
                                float* __restrict__ ss)
{
    const int c = threadIdx.x;
    if (c < NCH) {
        const float inv = 1.0f / (float)NPTS;
        float mu  = sums[c] * inv;
        float var = sums[NCH + c] * inv - mu * mu;
        float rs  = 1.0f / sqrtf(var + EPSV);
        float scv = gamma[c] * rs;
        ss[c]       = scv;
        ss[NCH + c] = beta[c] - mu * scv;
    }
}

// In-place bf16 y = relu(x*sc+sh); thread t slot j -> channel (t%8)*8+j
__global__ __launch_bounds__(256)
void bnrelu_bf16_kernel(unsigned short* __restrict__ x, const float* __restrict__ ss)
{
    const int t = threadIdx.x;
    const int c0 = (t & 7) * 8;
    float sc[8], sh[8];
#pragma unroll
    for (int j = 0; j < 8; ++j) { sc[j] = ss[c0 + j]; sh[j] = ss[NCH + c0 + j]; }
    const long nchunk = (long)NPTS * NCH / 8;
    const long stride = (long)gridDim.x * 256;
    ushort8* x8 = (ushort8*)x;
    for (long i = (long)blockIdx.x * 256 + t; i < nchunk; i += stride) {
        ushort8 v = x8[i];
#pragma unroll
        for (int j = 0; j < 8; ++j) {
            float f = fmaxf(fmaf(bf2f(v[j]), sc[j], sh[j]), 0.0f);
            v[j] = f2bf(f);
        }
        x8[i] = v;
    }
}

// In-place fp32 y = relu(x*sc+sh) (unchanged from R2)
__global__ __launch_bounds__(256)
void bnrelu_f32_kernel(float* __restrict__ x, const float* __restrict__ ss, long n4)
{
    const int t = threadIdx.x;
    const int c0 = (t * 4) & 63;
    const float4 sc = *(const float4*)&ss[c0];
    const float4 sh = *(const float4*)&ss[NCH + c0];
    const long stride = (long)gridDim.x * 256;
    float4* x4 = (float4*)x;
    for (long i = (long)blockIdx.x * 256 + t; i < n4; i += stride) {
        float4 v = x4[i];
        v.x = fmaxf(fmaf(v.x, sc.x, sh.x), 0.0f);
        v.y = fmaxf(fmaf(v.y, sc.y, sh.y), 0.0f);
        v.z = fmaxf(fmaf(v.z, sc.z, sh.z), 0.0f);
        v.w = fmaxf(fmaf(v.w, sc.w, sh.w), 0.0f);
        x4[i] = v;
    }
}

extern "C" void kernel_launch(void* const* d_in, const int* in_sizes, int n_in,
                              void* d_out, int out_size, void* d_ws, size_t ws_size,
                              hipStream_t stream)
{
    const float* feats  = (const float*)d_in[0];
    const float* W1     = (const float*)d_in[1];
    const float* W2     = (const float*)d_in[2];
    const float* gamma1 = (const float*)d_in[3];
    const float* beta1  = (const float*)d_in[4];
    const float* gamma2 = (const float*)d_in[5];
    const float* beta2  = (const float*)d_in[6];
    const int* nbr      = (const int*)d_in[7];
    const unsigned char* mask8 = (const unsigned char*)d_in[8];
    const int* mask32          = (const int*)d_in[8];
    float* out = (float*)d_out;

    // ---- workspace layout (all 16B-aligned offsets), ~192.7 MB total ----
    char* w = (char*)d_ws;
    unsigned short* h1  = (unsigned short*)w;                     // [N][64] bf16, 128 MB
    unsigned short* fb  = (unsigned short*)(w + 128000000);       // feats bf16, 64 MB
    unsigned short* wt1 = (unsigned short*)(w + 192000000);       // 110,592 B
    unsigned short* wt2 = (unsigned short*)(w + 192200704);       // 221,184 B
    float* stats        = (float*)(w + 192600000);                // 512 f32
    int*   mflag        = (int*)(w + 192700000);
    // stats: [0:128) sums1 | [128:256) ss1 | [256:384) sums2 | [384:512) ss2

    hipMemsetAsync(stats, 0, 512 * sizeof(float), stream);
    detect_mask_kernel<<<1, 256, 0, stream>>>((const unsigned int*)d_in[8], mflag);

    cvt_feats_kernel<<<2048, 256, 0, stream>>>(feats, fb);
    transpose_w_kernel<32><<<KNBR, 256, 0, stream>>>(W1, wt1);
    transpose_w_kernel<64><<<KNBR, 256, 0, stream>>>(W2, wt2);

    const int conv_grid = NPTS / 64;   // 15625, exact
    const long n4 = (long)NPTS * NCH / 4;

    conv_mfma_kernel<32, true><<<conv_grid, 256, 0, stream>>>(
        fb, wt1, nbr, mask8, mask32, mflag, h1);
    stats_bf16_kernel<<<1024, 256, 0, stream>>>(h1, stats);
    finalize_kernel<<<1, 64, 0, stream>>>(stats, gamma1, beta1, stats + 128);
    bnrelu_bf16_kernel<<<2048, 256, 0, stream>>>(h1, stats + 128);

    conv_mfma_kernel<64, false><<<conv_grid, 256, 0, stream>>>(
        h1, wt2, nbr, mask8, mask32, mflag, out);
    stats_f32_kernel<<<1024, 256, 0, stream>>>(out, stats + 256);
    finalize_kernel<<<1, 64, 0, stream>>>(stats + 256, gamma2, beta2, stats + 384);
    bnrelu_f32_kernel<<<2048, 256, 0, stream>>>(out, stats + 384, n4);
}

// Round 4
// 1676.015 us; speedup vs baseline: 3.2914x; 1.7385x over previous
//
#include <hip/hip_runtime.h>

#define NPTS 1000000
#define KNBR 27
#define NCH 64
#define EPSV 1e-5f

typedef __attribute__((ext_vector_type(8))) short bf16x8;   // 8 bf16 = 4 VGPRs
typedef __attribute__((ext_vector_type(4))) float f32x4;    // MFMA C/D frag
typedef __attribute__((ext_vector_type(8))) unsigned short ushort8;

__device__ inline unsigned short f2bf(float f) {            // RNE fp32->bf16
    unsigned int x = __float_as_uint(f);
    unsigned int r = x + 0x7FFFu + ((x >> 16) & 1u);
    return (unsigned short)(r >> 16);
}
__device__ inline float bf2f(unsigned short u) {
    return __uint_as_float(((unsigned int)u) << 16);
}

// ---------------------------------------------------------------------------
// Mask dtype autodetect (verified working R2/R3).
// ---------------------------------------------------------------------------
__global__ void detect_mask_kernel(const unsigned int* __restrict__ mask32,
                                   int* __restrict__ flag)
{
    __shared__ int cnt;
    if (threadIdx.x == 0) cnt = 0;
    __syncthreads();
    int c = 0;
    for (int i = threadIdx.x; i < 4096; i += 256)
        if (mask32[i] <= 1u) c++;
    atomicAdd(&cnt, c);
    __syncthreads();
    if (threadIdx.x == 0) *flag = (cnt >= 3900) ? 1 : 0;
}

// feats fp32 -> bf16
__global__ __launch_bounds__(256)
void cvt_feats_kernel(const float* __restrict__ in, unsigned short* __restrict__ outp)
{
    const long nchunk = (long)NPTS * 32 / 8;   // 4M
    const long stride = (long)gridDim.x * 256;
    const float4* f4 = (const float4*)in;
    ushort8* o8 = (ushort8*)outp;
    for (long i = (long)blockIdx.x * 256 + threadIdx.x; i < nchunk; i += stride) {
        float4 a = f4[2 * i], b = f4[2 * i + 1];
        ushort8 o;
        o[0] = f2bf(a.x); o[1] = f2bf(a.y); o[2] = f2bf(a.z); o[3] = f2bf(a.w);
        o[4] = f2bf(b.x); o[5] = f2bf(b.y); o[6] = f2bf(b.z); o[7] = f2bf(b.w);
        o8[i] = o;
    }
}

// ---------------------------------------------------------------------------
// W[k][ci][co] fp32 -> MFMA-fragment-ordered bf16:
//   wtf[k][ks][c][lane][j]  with  ci = ks*32 + (lane>>4)*8 + j,  co = c*16 + (lane&15)
// One B-load in the conv = one contiguous 1KB wave read.
// ---------------------------------------------------------------------------
template<int CIN>
__global__ __launch_bounds__(256)
void transpose_w_frag_kernel(const float* __restrict__ W, unsigned short* __restrict__ wtf)
{
    const int k = blockIdx.x;
    constexpr int TOT = CIN * 64;
    for (int e = threadIdx.x; e < TOT; e += 256) {
        // e = ((ks*4 + c)*64 + l)*8 + j
        const int j = e & 7, l = (e >> 3) & 63, c = (e >> 9) & 3, ks = e >> 11;
        const int ci = ks * 32 + (l >> 4) * 8 + j;
        const int co = c * 16 + (l & 15);
        wtf[(size_t)k * TOT + e] = f2bf(W[((size_t)k * CIN + ci) * 64 + co]);
    }
}

// ---------------------------------------------------------------------------
// MFMA conv. Block = 256 thr (4 waves) x 256 points; wave = 64 points x 64 couts.
// Per (k,ks): 4 contiguous B-loads (1KB each) + 4 gathered A-loads (16B/lane)
// feeding 16 independent MFMAs -> 8 loads in flight per step.
// BN stats (per-channel sum/sumsq) fused into the epilogue.
// ---------------------------------------------------------------------------
template<int CIN, bool OUT_BF16>
__global__ __launch_bounds__(256)
void conv_mfma_kernel(const unsigned short* __restrict__ src,  // [N][CIN] bf16
                      const unsigned short* __restrict__ wtf,  // frag-ordered W
                      const int* __restrict__ nbr,
                      const unsigned char* __restrict__ mask8,
                      const int* __restrict__ mask32,
                      const int* __restrict__ mflag,
                      void* __restrict__ outp,
                      float* __restrict__ sums)   // [64] sum | [64] sumsq
{
    constexpr int KS = CIN / 32;
    __shared__ int midx[256 * KNBR];        // 27.0 KB
    __shared__ float sred[64], qred[64];

    const int t = threadIdx.x;
    const int pbase = blockIdx.x * 256;

    if (t < 64) { sred[t] = 0.f; qred[t] = 0.f; }

    // ---- stage merged nbr+mask (-1 = skip) ----
    const bool m32 = (*mflag != 0);
    for (int i = t; i < 256 * KNBR; i += 256) {
        const int p = i / KNBR;             // magic-mul div by 27
        int v = -1;
        if (pbase + p < NPTS) {
            const int gi = pbase * KNBR + i;
            const bool mv = m32 ? (mask32[gi] != 0) : (mask8[gi] != 0);
            v = mv ? nbr[gi] : -1;
        }
        midx[i] = v;
    }
    __syncthreads();

    const int wave = t >> 6;
    const int lane = t & 63;
    const int lr = lane & 15;    // A row within 16-row frag / output col within coltile
    const int kg = lane >> 4;    // k-subgroup
    const int wpt = wave * 64;   // wave's first point within block

    f32x4 acc[4][4];             // [c coltile][a rowtile]
#pragma unroll
    for (int c = 0; c < 4; ++c)
#pragma unroll
        for (int a = 0; a < 4; ++a) acc[c][a] = (f32x4){0.f, 0.f, 0.f, 0.f};

    const bf16x8 zero8 = {0, 0, 0, 0, 0, 0, 0, 0};
    const int mbase0 = (wpt + lr) * KNBR;   // + a*16*KNBR + k

    for (int k = 0; k < KNBR; ++k) {
#pragma unroll
        for (int ks = 0; ks < KS; ++ks) {
            bf16x8 b[4];
#pragma unroll
            for (int c = 0; c < 4; ++c)
                b[c] = *(const bf16x8*)(wtf + (size_t)k * (CIN * 64)
                                            + ((ks * 4 + c) * 64 + lane) * 8);
            bf16x8 a[4];
#pragma unroll
            for (int ai = 0; ai < 4; ++ai) {
                const int mi = midx[mbase0 + ai * (16 * KNBR) + k];
                a[ai] = zero8;
                if (mi >= 0)
                    a[ai] = *(const bf16x8*)(src + (size_t)mi * CIN + ks * 32 + kg * 8);
            }
#pragma unroll
            for (int c = 0; c < 4; ++c)
#pragma unroll
                for (int ai = 0; ai < 4; ++ai)
                    acc[c][ai] = __builtin_amdgcn_mfma_f32_16x16x32_bf16(
                        a[ai], b[c], acc[c][ai], 0, 0, 0);
        }
    }

    // ---- epilogue: D col=lr, row=kg*4+r (verified R3); fused BN stats ----
    float s[4], q[4];
#pragma unroll
    for (int c = 0; c < 4; ++c) { s[c] = 0.f; q[c] = 0.f; }

#pragma unroll
    for (int c = 0; c < 4; ++c) {
#pragma unroll
        for (int ai = 0; ai < 4; ++ai) {
#pragma unroll
            for (int r = 0; r < 4; ++r) {
                const float v = acc[c][ai][r];
                s[c] += v;
                q[c] = fmaf(v, v, q[c]);
                const int row = pbase + wpt + ai * 16 + kg * 4 + r;
                if (row < NPTS) {
                    if (OUT_BF16)
                        ((unsigned short*)outp)[(size_t)row * NCH + c * 16 + lr] = f2bf(v);
                    else
                        ((float*)outp)[(size_t)row * NCH + c * 16 + lr] = v;
                }
            }
        }
    }
#pragma unroll
    for (int c = 0; c < 4; ++c) {
        atomicAdd(&sred[c * 16 + lr], s[c]);
        atomicAdd(&qred[c * 16 + lr], q[c]);
    }
    __syncthreads();
    if (t < 64) {
        atomicAdd(&sums[t], sred[t]);
        atomicAdd(&sums[64 + t], qred[t]);
    }
}

// sums -> folded scale/shift:  bn(x) = x*scale + shift
__global__ void finalize_kernel(const float* __restrict__ sums,
                                const float* __restrict__ gamma,
                                const float* __restrict__ beta,
                                float* __restrict__ ss)
{
    const int c = threadIdx.x;
    if (c < NCH) {
        const float inv = 1.0f / (float)NPTS;
        float mu  = sums[c] * inv;
        float var = sums[NCH + c] * inv - mu * mu;
        float rs  = 1.0f / sqrtf(var + EPSV);
        float scv = gamma[c] * rs;
        ss[c]       = scv;
        ss[NCH + c] = beta[c] - mu * scv;
    }
}

// In-place bf16 y = relu(x*sc+sh); thread t slot j -> channel (t%8)*8+j
__global__ __launch_bounds__(256)
void bnrelu_bf16_kernel(unsigned short* __restrict__ x, const float* __restrict__ ss)
{
    const int t = threadIdx.x;
    const int c0 = (t & 7) * 8;
    float sc[8], sh[8];
#pragma unroll
    for (int j = 0; j < 8; ++j) { sc[j] = ss[c0 + j]; sh[j] = ss[NCH + c0 + j]; }
    const long nchunk = (long)NPTS * NCH / 8;
    const long stride = (long)gridDim.x * 256;
    ushort8* x8 = (ushort8*)x;
    for (long i = (long)blockIdx.x * 256 + t; i < nchunk; i += stride) {
        ushort8 v = x8[i];
#pragma unroll
        for (int j = 0; j < 8; ++j) {
            float f = fmaxf(fmaf(bf2f(v[j]), sc[j], sh[j]), 0.0f);
            v[j] = f2bf(f);
        }
        x8[i] = v;
    }
}

// In-place fp32 y = relu(x*sc+sh)
__global__ __launch_bounds__(256)
void bnrelu_f32_kernel(float* __restrict__ x, const float* __restrict__ ss, long n4)
{
    const int t = threadIdx.x;
    const int c0 = (t * 4) & 63;
    const float4 sc = *(const float4*)&ss[c0];
    const float4 sh = *(const float4*)&ss[NCH + c0];
    const long stride = (long)gridDim.x * 256;
    float4* x4 = (float4*)x;
    for (long i = (long)blockIdx.x * 256 + t; i < n4; i += stride) {
        float4 v = x4[i];
        v.x = fmaxf(fmaf(v.x, sc.x, sh.x), 0.0f);
        v.y = fmaxf(fmaf(v.y, sc.y, sh.y), 0.0f);
        v.z = fmaxf(fmaf(v.z, sc.z, sh.z), 0.0f);
        v.w = fmaxf(fmaf(v.w, sc.w, sh.w), 0.0f);
        x4[i] = v;
    }
}

extern "C" void kernel_launch(void* const* d_in, const int* in_sizes, int n_in,
                              void* d_out, int out_size, void* d_ws, size_t ws_size,
                              hipStream_t stream)
{
    const float* feats  = (const float*)d_in[0];
    const float* W1     = (const float*)d_in[1];
    const float* W2     = (const float*)d_in[2];
    const float* gamma1 = (const float*)d_in[3];
    const float* beta1  = (const float*)d_in[4];
    const float* gamma2 = (const float*)d_in[5];
    const float* beta2  = (const float*)d_in[6];
    const int* nbr      = (const int*)d_in[7];
    const unsigned char* mask8 = (const unsigned char*)d_in[8];
    const int* mask32          = (const int*)d_in[8];
    float* out = (float*)d_out;

    // ---- workspace layout ----
    char* w = (char*)d_ws;
    unsigned short* h1  = (unsigned short*)w;                     // [N][64] bf16, 128 MB
    unsigned short* fb  = (unsigned short*)(w + 128000000);       // feats bf16, 64 MB
    unsigned short* wt1 = (unsigned short*)(w + 192000000);       // 110,592 B frag-order
    unsigned short* wt2 = (unsigned short*)(w + 192200704);       // 221,184 B frag-order
    float* stats        = (float*)(w + 192600000);                // 512 f32
    int*   mflag        = (int*)(w + 192700000);
    // stats: [0:128) sums1 | [128:256) ss1 | [256:384) sums2 | [384:512) ss2

    hipMemsetAsync(stats, 0, 512 * sizeof(float), stream);
    detect_mask_kernel<<<1, 256, 0, stream>>>((const unsigned int*)d_in[8], mflag);

    cvt_feats_kernel<<<2048, 256, 0, stream>>>(feats, fb);
    transpose_w_frag_kernel<32><<<KNBR, 256, 0, stream>>>(W1, wt1);
    transpose_w_frag_kernel<64><<<KNBR, 256, 0, stream>>>(W2, wt2);

    const int conv_grid = (NPTS + 255) / 256;   // 3907
    const long n4 = (long)NPTS * NCH / 4;

    conv_mfma_kernel<32, true><<<conv_grid, 256, 0, stream>>>(
        fb, wt1, nbr, mask8, mask32, mflag, h1, stats);
    finalize_kernel<<<1, 64, 0, stream>>>(stats, gamma1, beta1, stats + 128);
    bnrelu_bf16_kernel<<<2048, 256, 0, stream>>>(h1, stats + 128);

    conv_mfma_kernel<64, false><<<conv_grid, 256, 0, stream>>>(
        h1, wt2, nbr, mask8, mask32, mflag, out, stats + 256);
    finalize_kernel<<<1, 64, 0, stream>>>(stats + 256, gamma2, beta2, stats + 384);
    bnrelu_f32_kernel<<<2048, 256, 0, stream>>>(out, stats + 384, n4);
}

// Round 6
// 1634.364 us; speedup vs baseline: 3.3753x; 1.0255x over previous
//
#include <hip/hip_runtime.h>

#define NPTS 1000000
#define KNBR 27
#define NCH 64
#define EPSV 1e-5f

typedef __attribute__((ext_vector_type(8))) short bf16x8;   // 8 bf16 = 4 VGPRs
typedef __attribute__((ext_vector_type(4))) float f32x4;    // MFMA C/D frag / vec4 f32
typedef __attribute__((ext_vector_type(8))) unsigned short ushort8;

__device__ inline unsigned short f2bf(float f) {            // RNE fp32->bf16
    unsigned int x = __float_as_uint(f);
    unsigned int r = x + 0x7FFFu + ((x >> 16) & 1u);
    return (unsigned short)(r >> 16);
}
__device__ inline float bf2f(unsigned short u) {
    return __uint_as_float(((unsigned int)u) << 16);
}

// ---------------------------------------------------------------------------
// Mask dtype autodetect (verified working R2-R4).
// ---------------------------------------------------------------------------
__global__ void detect_mask_kernel(const unsigned int* __restrict__ mask32,
                                   int* __restrict__ flag)
{
    __shared__ int cnt;
    if (threadIdx.x == 0) cnt = 0;
    __syncthreads();
    int c = 0;
    for (int i = threadIdx.x; i < 4096; i += 256)
        if (mask32[i] <= 1u) c++;
    atomicAdd(&cnt, c);
    __syncthreads();
    if (threadIdx.x == 0) *flag = (cnt >= 3900) ? 1 : 0;
}

// feats fp32 -> bf16
__global__ __launch_bounds__(256)
void cvt_feats_kernel(const float* __restrict__ in, unsigned short* __restrict__ outp)
{
    const long nchunk = (long)NPTS * 32 / 8;   // 4M
    const long stride = (long)gridDim.x * 256;
    const float4* f4 = (const float4*)in;
    ushort8* o8 = (ushort8*)outp;
    for (long i = (long)blockIdx.x * 256 + threadIdx.x; i < nchunk; i += stride) {
        float4 a = f4[2 * i], b = f4[2 * i + 1];
        ushort8 o;
        o[0] = f2bf(a.x); o[1] = f2bf(a.y); o[2] = f2bf(a.z); o[3] = f2bf(a.w);
        o[4] = f2bf(b.x); o[5] = f2bf(b.y); o[6] = f2bf(b.z); o[7] = f2bf(b.w);
        o8[i] = o;
    }
}

// ---------------------------------------------------------------------------
// W[k][ci][co] fp32 -> MFMA-fragment-ordered bf16:
//   wtf[k][ks][c][lane][j]  with  ci = ks*32 + (lane>>4)*8 + j,  co = c*16 + (lane&15)
// ---------------------------------------------------------------------------
template<int CIN>
__global__ __launch_bounds__(256)
void transpose_w_frag_kernel(const float* __restrict__ W, unsigned short* __restrict__ wtf)
{
    const int k = blockIdx.x;
    constexpr int TOT = CIN * 64;
    for (int e = threadIdx.x; e < TOT; e += 256) {
        // e = ((ks*4 + c)*64 + l)*8 + j
        const int j = e & 7, l = (e >> 3) & 63, c = (e >> 9) & 3, ks = e >> 11;
        const int ci = ks * 32 + (l >> 4) * 8 + j;
        const int co = c * 16 + (l & 15);
        wtf[(size_t)k * TOT + e] = f2bf(W[((size_t)k * CIN + ci) * 64 + co]);
    }
}

// ---------------------------------------------------------------------------
// MFMA conv. Block = 256 thr (4 waves) x 128 points; wave = 32 points x 64 couts.
// acc = 4x2 f32x4 = 32 AGPR -> with ~70 VGPR fits the 128 bucket => 4 waves/SIMD
// (launch_bounds(256,4)). Per (k,ks): 4 contiguous B-loads + 2 gathered A-loads
// feeding 8 MFMAs. BN stats fused into epilogue. Final-output stores are
// nontemporal (never re-read) so h1 stays L3-resident for the gathers.
// ---------------------------------------------------------------------------
template<int CIN, bool OUT_BF16>
__global__ __launch_bounds__(256, 4)
void conv_mfma_kernel(const unsigned short* __restrict__ src,  // [N][CIN] bf16
                      const unsigned short* __restrict__ wtf,  // frag-ordered W
                      const int* __restrict__ nbr,
                      const unsigned char* __restrict__ mask8,
                      const int* __restrict__ mask32,
                      const int* __restrict__ mflag,
                      void* __restrict__ outp,
                      float* __restrict__ sums)   // [64] sum | [64] sumsq
{
    constexpr int KS = CIN / 32;
    __shared__ int midx[128 * KNBR];        // 13.5 KB
    __shared__ float sred[64], qred[64];

    const int t = threadIdx.x;
    const int pbase = blockIdx.x * 128;

    if (t < 64) { sred[t] = 0.f; qred[t] = 0.f; }

    // ---- stage merged nbr+mask (-1 = skip) ----
    const bool m32 = (*mflag != 0);
    for (int i = t; i < 128 * KNBR; i += 256) {
        const int p = i / KNBR;
        int v = -1;
        if (pbase + p < NPTS) {
            const int gi = pbase * KNBR + i;
            const bool mv = m32 ? (mask32[gi] != 0) : (mask8[gi] != 0);
            v = mv ? nbr[gi] : -1;
        }
        midx[i] = v;
    }
    __syncthreads();

    const int wave = t >> 6;
    const int lane = t & 63;
    const int lr = lane & 15;    // A row within 16-row frag / output col within coltile
    const int kg = lane >> 4;    // k-subgroup
    const int wpt = wave * 32;   // wave's first point within block

    f32x4 acc[4][2];             // [c coltile][a rowtile]
#pragma unroll
    for (int c = 0; c < 4; ++c)
#pragma unroll
        for (int a = 0; a < 2; ++a) acc[c][a] = (f32x4){0.f, 0.f, 0.f, 0.f};

    const bf16x8 zero8 = {0, 0, 0, 0, 0, 0, 0, 0};
    const int mbase0 = (wpt + lr) * KNBR;   // + ai*16*KNBR + k

    for (int k = 0; k < KNBR; ++k) {
#pragma unroll
        for (int ks = 0; ks < KS; ++ks) {
            bf16x8 a[2];
#pragma unroll
            for (int ai = 0; ai < 2; ++ai) {
                const int mi = midx[mbase0 + ai * (16 * KNBR) + k];
                a[ai] = zero8;
                if (mi >= 0)
                    a[ai] = *(const bf16x8*)(src + (size_t)mi * CIN + ks * 32 + kg * 8);
            }
            bf16x8 b[4];
#pragma unroll
            for (int c = 0; c < 4; ++c)
                b[c] = *(const bf16x8*)(wtf + (size_t)k * (CIN * 64)
                                            + ((ks * 4 + c) * 64 + lane) * 8);
#pragma unroll
            for (int c = 0; c < 4; ++c)
#pragma unroll
                for (int ai = 0; ai < 2; ++ai)
                    acc[c][ai] = __builtin_amdgcn_mfma_f32_16x16x32_bf16(
                        a[ai], b[c], acc[c][ai], 0, 0, 0);
        }
    }

    // ---- epilogue: D col=lr, row=kg*4+r (verified R3/R4); fused BN stats ----
    float s[4], q[4];
#pragma unroll
    for (int c = 0; c < 4; ++c) { s[c] = 0.f; q[c] = 0.f; }

#pragma unroll
    for (int c = 0; c < 4; ++c) {
#pragma unroll
        for (int ai = 0; ai < 2; ++ai) {
#pragma unroll
            for (int r = 0; r < 4; ++r) {
                const float v = acc[c][ai][r];
                s[c] += v;
                q[c] = fmaf(v, v, q[c]);
                const int row = pbase + wpt + ai * 16 + kg * 4 + r;
                if (row < NPTS) {
                    if (OUT_BF16)
                        ((unsigned short*)outp)[(size_t)row * NCH + c * 16 + lr] = f2bf(v);
                    else  // final output: never re-read on device -> bypass L3
                        __builtin_nontemporal_store(
                            v, &((float*)outp)[(size_t)row * NCH + c * 16 + lr]);
                }
            }
        }
    }
#pragma unroll
    for (int c = 0; c < 4; ++c) {
        atomicAdd(&sred[c * 16 + lr], s[c]);
        atomicAdd(&qred[c * 16 + lr], q[c]);
    }
    __syncthreads();
    if (t < 64) {
        atomicAdd(&sums[t], sred[t]);
        atomicAdd(&sums[64 + t], qred[t]);
    }
}

// sums -> folded scale/shift:  bn(x) = x*scale + shift
__global__ void finalize_kernel(const float* __restrict__ sums,
                                const float* __restrict__ gamma,
                                const float* __restrict__ beta,
                                float* __restrict__ ss)
{
    const int c = threadIdx.x;
    if (c < NCH) {
        const float inv = 1.0f / (float)NPTS;
        float mu  = sums[c] * inv;
        float var = sums[NCH + c] * inv - mu * mu;
        float rs  = 1.0f / sqrtf(var + EPSV);
        float scv = gamma[c] * rs;
        ss[c]       = scv;
        ss[NCH + c] = beta[c] - mu * scv;
    }
}

// In-place bf16 y = relu(x*sc+sh); thread t slot j -> channel (t%8)*8+j.
// h1 must STAY cached (conv2 gathers it) -> normal loads/stores.
__global__ __launch_bounds__(256)
void bnrelu_bf16_kernel(unsigned short* __restrict__ x, const float* __restrict__ ss)
{
    const int t = threadIdx.x;
    const int c0 = (t & 7) * 8;
    float sc[8], sh[8];
#pragma unroll
    for (int j = 0; j < 8; ++j) { sc[j] = ss[c0 + j]; sh[j] = ss[NCH + c0 + j]; }
    const long nchunk = (long)NPTS * NCH / 8;
    const long stride = (long)gridDim.x * 256;
    ushort8* x8 = (ushort8*)x;
    for (long i = (long)blockIdx.x * 256 + t; i < nchunk; i += stride) {
        ushort8 v = x8[i];
#pragma unroll
        for (int j = 0; j < 8; ++j) {
            float f = fmaxf(fmaf(bf2f(v[j]), sc[j], sh[j]), 0.0f);
            v[j] = f2bf(f);
        }
        x8[i] = v;
    }
}

// In-place fp32 y = relu(x*sc+sh) on the final output: fully nontemporal.
// Uses clang ext_vector f32x4 (NOT HIP float4) — nontemporal builtins require
// a pointer to scalar-or-clang-vector type.
__global__ __launch_bounds__(256)
void bnrelu_f32_kernel(float* __restrict__ x, const float* __restrict__ ss, long n4)
{
    const int t = threadIdx.x;
    const int c0 = (t * 4) & 63;
    const float4 sc = *(const float4*)&ss[c0];
    const float4 sh = *(const float4*)&ss[NCH + c0];
    const long stride = (long)gridDim.x * 256;
    f32x4* x4 = (f32x4*)x;
    for (long i = (long)blockIdx.x * 256 + t; i < n4; i += stride) {
        f32x4 v = __builtin_nontemporal_load(&x4[i]);
        v.x = fmaxf(fmaf(v.x, sc.x, sh.x), 0.0f);
        v.y = fmaxf(fmaf(v.y, sc.y, sh.y), 0.0f);
        v.z = fmaxf(fmaf(v.z, sc.z, sh.z), 0.0f);
        v.w = fmaxf(fmaf(v.w, sc.w, sh.w), 0.0f);
        __builtin_nontemporal_store(v, &x4[i]);
    }
}

extern "C" void kernel_launch(void* const* d_in, const int* in_sizes, int n_in,
                              void* d_out, int out_size, void* d_ws, size_t ws_size,
                              hipStream_t stream)
{
    const float* feats  = (const float*)d_in[0];
    const float* W1     = (const float*)d_in[1];
    const float* W2     = (const float*)d_in[2];
    const float* gamma1 = (const float*)d_in[3];
    const float* beta1  = (const float*)d_in[4];
    const float* gamma2 = (const float*)d_in[5];
    const float* beta2  = (const float*)d_in[6];
    const int* nbr      = (const int*)d_in[7];
    const unsigned char* mask8 = (const unsigned char*)d_in[8];
    const int* mask32          = (const int*)d_in[8];
    float* out = (float*)d_out;

    // ---- workspace layout ----
    char* w = (char*)d_ws;
    unsigned short* h1  = (unsigned short*)w;                     // [N][64] bf16, 128 MB
    unsigned short* fb  = (unsigned short*)(w + 128000000);       // feats bf16, 64 MB
    unsigned short* wt1 = (unsigned short*)(w + 192000000);       // 110,592 B frag-order
    unsigned short* wt2 = (unsigned short*)(w + 192200704);       // 221,184 B frag-order
    float* stats        = (float*)(w + 192600000);                // 512 f32
    int*   mflag        = (int*)(w + 192700000);
    // stats: [0:128) sums1 | [128:256) ss1 | [256:384) sums2 | [384:512) ss2

    (void)hipMemsetAsync(stats, 0, 512 * sizeof(float), stream);
    detect_mask_kernel<<<1, 256, 0, stream>>>((const unsigned int*)d_in[8], mflag);

    cvt_feats_kernel<<<2048, 256, 0, stream>>>(feats, fb);
    transpose_w_frag_kernel<32><<<KNBR, 256, 0, stream>>>(W1, wt1);
    transpose_w_frag_kernel<64><<<KNBR, 256, 0, stream>>>(W2, wt2);

    const int conv_grid = (NPTS + 127) / 128;   // 7813
    const long n4 = (long)NPTS * NCH / 4;

    conv_mfma_kernel<32, true><<<conv_grid, 256, 0, stream>>>(
        fb, wt1, nbr, mask8, mask32, mflag, h1, stats);
    finalize_kernel<<<1, 64, 0, stream>>>(stats, gamma1, beta1, stats + 128);
    bnrelu_bf16_kernel<<<2048, 256, 0, stream>>>(h1, stats + 128);

    conv_mfma_kernel<64, false><<<conv_grid, 256, 0, stream>>>(
        h1, wt2, nbr, mask8, mask32, mflag, out, stats + 256);
    finalize_kernel<<<1, 64, 0, stream>>>(stats + 256, gamma2, beta2, stats + 384);
    bnrelu_f32_kernel<<<2048, 256, 0, stream>>>(out, stats + 384, n4);
}